// Round 11
// baseline (204.744 us; speedup 1.0000x reference)
//
#include <hip/hip_runtime.h>

#define M_TOK 8192
#define N_OUT 4096
#define K_IN  4096

#define AS1 __attribute__((address_space(1)))
#define AS3 __attribute__((address_space(3)))

typedef __attribute__((ext_vector_type(4))) int i32x4;
typedef __attribute__((ext_vector_type(16))) int i32x16;

// inline-asm ds_read_b128: invisible to compiler AA; ordering is OURS via
// counted lgkmcnt + sched_barrier(0) (rule 18).
template <int OFF>
__device__ __forceinline__ i32x4 dsri(unsigned addr) {
    i32x4 r;
    asm volatile("ds_read_b128 %0, %1 offset:%2" : "=v"(r) : "v"(addr), "n"(OFF));
    return r;
}

// ---------------- prepass 1: per-token absmax quant of x (row-major out) ----

__global__ __launch_bounds__(256) void quant_x_kernel(
    const float* __restrict__ x, signed char* __restrict__ xq,
    float* __restrict__ tok_scale)
{
    const int row = blockIdx.x;
    const float4* xr = reinterpret_cast<const float4*>(x + (size_t)row * K_IN);
    const int t = threadIdx.x;
    float4 v[4];
    float m = 0.f;
#pragma unroll
    for (int i = 0; i < 4; ++i) {
        v[i] = xr[t + 256 * i];
        m = fmaxf(m, fmaxf(fmaxf(fabsf(v[i].x), fabsf(v[i].y)),
                           fmaxf(fabsf(v[i].z), fabsf(v[i].w))));
    }
#pragma unroll
    for (int off = 32; off >= 1; off >>= 1)
        m = fmaxf(m, __shfl_xor(m, off, 64));
    __shared__ float wmax[4];
    if ((t & 63) == 0) wmax[t >> 6] = m;
    __syncthreads();
    m = fmaxf(fmaxf(wmax[0], wmax[1]), fmaxf(wmax[2], wmax[3]));
    if (t == 0) tok_scale[row] = m * (1.0f / 127.0f);
    const float inv = (m > 0.f) ? (127.0f / m) : 0.f;
    int* xqi = reinterpret_cast<int*>(xq + (size_t)row * K_IN);
#pragma unroll
    for (int i = 0; i < 4; ++i) {
        const int q0 = __float2int_rn(v[i].x * inv) & 255;
        const int q1 = __float2int_rn(v[i].y * inv) & 255;
        const int q2 = __float2int_rn(v[i].z * inv) & 255;
        const int q3 = __float2int_rn(v[i].w * inv) & 255;
        xqi[t + 256 * i] = q0 | (q1 << 8) | (q2 << 16) | (q3 << 24);
    }
}

// ---------------- prepass 1b: retile xq8 row-major -> frag-tiled -------------

__global__ __launch_bounds__(256) void retile_x_kernel(
    const signed char* __restrict__ xq8, signed char* __restrict__ xqF)
{
    __shared__ __align__(16) char lds[32768];
    const int t = threadIdx.x;
    const int rb = blockIdx.x >> 2;
    const int kc = blockIdx.x & 3;

    const size_t srcBase = (size_t)rb * 32 * K_IN + (size_t)kc * 1024;
#pragma unroll
    for (int j = 0; j < 8; ++j) {
        const int u = j * 256 + t;
        const int row = u >> 6, gc = u & 63;
        const i32x4 v = *reinterpret_cast<const i32x4*>(
            xq8 + srcBase + (size_t)row * K_IN + gc * 16);
        *reinterpret_cast<i32x4*>(
            lds + ((row * 64 + (gc ^ (row & 7))) * 16)) = v;
    }
    __syncthreads();

    const int l = t & 63;
    const int W = t >> 6;
    const int row = l & 31;
    const int hi = l >> 5;
    i32x4* dst0 = reinterpret_cast<i32x4*>(xqF) +
                  ((size_t)rb * 128 + kc * 32) * 64 + l;
#pragma unroll
    for (int i = 0; i < 8; ++i) {
        const int kfl = W * 8 + i;
        const int gc = (kfl * 2 + hi) ^ (row & 7);
        const i32x4 v = *reinterpret_cast<const i32x4*>(
            lds + ((row * 64 + gc) * 16));
        dst0[(size_t)kfl * 64] = v;
    }
}

// ---------------- prepass 2: pack Wq int32 -> int8, frag-tiled ---------------

__global__ __launch_bounds__(256) void pack_w_frag_kernel(
    const int* __restrict__ wq, signed char* __restrict__ wqF)
{
    const int t = threadIdx.x;
    const int l = t & 63;
    const int W = t >> 6;
    const int rb = blockIdx.x >> 3;
    const int pc = blockIdx.x & 7;
    const int r = rb * 32 + (l & 31);
    const int4* wr4 = reinterpret_cast<const int4*>(wq) + (size_t)r * 1024;
    i32x4* outF = reinterpret_cast<i32x4*>(wqF) + (size_t)rb * 128 * 64 + l;
#pragma unroll
    for (int q = 0; q < 4; ++q) {
        const int f = W + 4 * (pc * 4 + q);
        const int c4 = f * 8 + (l >> 5) * 4;
        i32x4 o;
#pragma unroll
        for (int j = 0; j < 4; ++j) {
            const int4 a = wr4[c4 + j];
            o[j] = (a.x & 255) | ((a.y & 255) << 8) | ((a.z & 255) << 16) | ((a.w & 255) << 24);
        }
        outF[(size_t)f * 64] = o;
    }
}

// ------- int8 GEMM R11: A via LDS (frag-linear, ring-4), B DIRECT-TO-REG -----
// C = Xq[M,K]*Wq8[N,K]^T; out = acc*ts[row]*(rs[col]/127)+bias.
// LDS port now carries A only: 64KB read + 16KB write per tile (~960 cyc)
// < MFMA 1165 cyc -> MFMA-bound. B frags (1KB contiguous in frag-tiled wqF)
// load straight to regs, double-buffered X/Y, issued one body ahead
// (compiler-managed waits). Manual vmcnt(2) boundary guards the A-glds ring:
// g(T+2) is always >=6 ops older than the 2 youngest -> drained under any
// compiler ordering of B loads. A lgkm: entry lgkm(4) (C_A0-3 ready, <=4 old
// outstanding), mid lgkm(8) (drains C_A4-7, allows N's 8).

#define BKB 64
#define NKT (K_IN / BKB)   // 64
#define SLOT 16384         // A-only: 16 frags x 1KB
#define NSLOT 4

#define MFMA(a, b, c) c = __builtin_amdgcn_mfma_i32_32x32x32_i8(a, b, c, 0, 0, 0)

// 8 A reads: kh0 frags (A0-3) then kh1 (A4-7)
#define RD8(P, aB)                             \
    P##_A0 = dsri<0>(aB);                      \
    P##_A1 = dsri<2048>(aB);                   \
    P##_A2 = dsri<4096>(aB);                   \
    P##_A3 = dsri<6144>(aB);                   \
    P##_A4 = dsri<1024>(aB);                   \
    P##_A5 = dsri<3072>(aB);                   \
    P##_A6 = dsri<5120>(aB);                   \
    P##_A7 = dsri<7168>(aB);

// 4 B frag loads for tile TT (plain C++; compiler tracks deps/waits)
#define RDB(P, TT)                                             \
    P##_B0 = bSrc[(size_t)((TT) * 2 + 0) * 64];                \
    P##_B1 = bSrc[(size_t)(128 + (TT) * 2 + 0) * 64];          \
    P##_B2 = bSrc[(size_t)((TT) * 2 + 1) * 64];                \
    P##_B3 = bSrc[(size_t)(128 + (TT) * 2 + 1) * 64];

#define CL8_0(P)                                              \
    MFMA(P##_A0, P##_B0, acc00); MFMA(P##_A0, P##_B1, acc01); \
    MFMA(P##_A1, P##_B0, acc10); MFMA(P##_A1, P##_B1, acc11); \
    MFMA(P##_A2, P##_B0, acc20); MFMA(P##_A2, P##_B1, acc21); \
    MFMA(P##_A3, P##_B0, acc30); MFMA(P##_A3, P##_B1, acc31);

#define CL8_1(P)                                              \
    MFMA(P##_A4, P##_B2, acc00); MFMA(P##_A4, P##_B3, acc01); \
    MFMA(P##_A5, P##_B2, acc10); MFMA(P##_A5, P##_B3, acc11); \
    MFMA(P##_A6, P##_B2, acc20); MFMA(P##_A6, P##_B3, acc21); \
    MFMA(P##_A7, P##_B2, acc30); MFMA(P##_A7, P##_B3, acc31);

#define GBODY(T, C, N, DO_STAGE)                                          \
    {                                                                     \
        asm volatile("s_waitcnt lgkmcnt(4)" ::: "memory");                \
        __builtin_amdgcn_sched_barrier(0);                                \
        __builtin_amdgcn_s_setprio(1);                                    \
        CL8_0(C)                                                          \
        __builtin_amdgcn_s_setprio(0);                                    \
        __builtin_amdgcn_sched_barrier(0);                                \
        const unsigned aN_ = aBase + (unsigned)((((T) + 1) & 3) * SLOT);  \
        RD8(N, aN_)                                                       \
        RDB(N, (T) + 1)                                                   \
        if (DO_STAGE) stageA((T) + 3);                                    \
        asm volatile("s_waitcnt lgkmcnt(8)" ::: "memory");                \
        __builtin_amdgcn_sched_barrier(0);                                \
        __builtin_amdgcn_s_setprio(1);                                    \
        CL8_1(C)                                                          \
        __builtin_amdgcn_s_setprio(0);                                    \
        __builtin_amdgcn_sched_barrier(0);                                \
        asm volatile("s_waitcnt vmcnt(2)" ::: "memory");                  \
        __builtin_amdgcn_sched_barrier(0);                                \
        __builtin_amdgcn_s_barrier();                                     \
        __builtin_amdgcn_sched_barrier(0);                                \
    }

#define GFINAL(C)                                                         \
    {                                                                     \
        asm volatile("s_waitcnt lgkmcnt(4)" ::: "memory");                \
        __builtin_amdgcn_sched_barrier(0);                                \
        __builtin_amdgcn_s_setprio(1);                                    \
        CL8_0(C)                                                          \
        __builtin_amdgcn_s_setprio(0);                                    \
        asm volatile("s_waitcnt lgkmcnt(0)" ::: "memory");                \
        __builtin_amdgcn_sched_barrier(0);                                \
        __builtin_amdgcn_s_setprio(1);                                    \
        CL8_1(C)                                                          \
        __builtin_amdgcn_s_setprio(0);                                    \
        __builtin_amdgcn_sched_barrier(0);                                \
    }

__global__ __launch_bounds__(512, 2) void qgemm_i8b_kernel(
    const signed char* __restrict__ xqF,
    const signed char* __restrict__ wqF,
    const float* __restrict__ tok_scale,
    const float* __restrict__ row_scales,
    const float* __restrict__ bias,
    float* __restrict__ out)
{
    __shared__ __align__(16) char smem[NSLOT * SLOT + 1024];  // 65 KiB (A-only)

    const int tid = threadIdx.x;
    const int l = tid & 63;
    const int w = tid >> 6;      // 0..7
    const int wr = w >> 2;       // 0..1
    const int wc = w & 3;        // 0..3

    // XCD-aware bijective swizzle (nwg = 512, 512 % 8 == 0)
    const int bid = blockIdx.x;
    const int swz = (bid & 7) * 64 + (bid >> 3);
    const int bm = swz >> 4;     // 0..31
    const int bn = swz & 15;     // 0..15

    // ---- A staging: wave w stages A frags {2w, 2w+1} of each tile ----
    const signed char* aS = xqF + ((size_t)(bm * 8 + w) * 128) * 1024 + (size_t)l * 16;
    char* aDst = smem + w * 2048;

    auto stageA = [&](int tt) {
        const int sb = (tt & 3) * SLOT;
        const signed char* a0 = aS + (size_t)tt * 2048;
        __builtin_amdgcn_global_load_lds((const AS1 void*)a0,          (AS3 void*)(aDst + sb),        16, 0, 0);
        __builtin_amdgcn_global_load_lds((const AS1 void*)(a0 + 1024), (AS3 void*)(aDst + sb + 1024), 16, 0, 0);
    };

    // ---- B direct-to-reg source: wave (wr,wc) needs row-blocks bn*8+wc*2+{0,1} ----
    // frag (rbB, kf) base + nb adds 128 frags; kf = T*2 + kh; per-lane l*16.
    const i32x4* bSrc = reinterpret_cast<const i32x4*>(
        wqF + ((size_t)(bn * 8 + wc * 2) * 128) * 1024) + l;

    // ---- fragment-linear A ds_read base ----
    const unsigned sbase = (unsigned)(uintptr_t)(AS3 char*)smem;
    const unsigned aBase = sbase + (unsigned)(wr * 8192 + l * 16);  // + slot + (mb*2+kh)*1024

    i32x16 acc00 = {0}, acc01 = {0}, acc10 = {0}, acc11 = {0};
    i32x16 acc20 = {0}, acc21 = {0}, acc30 = {0}, acc31 = {0};

    i32x4 X_A0, X_A1, X_A2, X_A3, X_A4, X_A5, X_A6, X_A7, X_B0, X_B1, X_B2, X_B3;
    i32x4 Y_A0, Y_A1, Y_A2, Y_A3, Y_A4, Y_A5, Y_A6, Y_A7, Y_B0, Y_B1, Y_B2, Y_B3;

    // ---- prologue ----
    RDB(X, 0)                          // B tile 0 -> regs (compiler-managed)
    stageA(0); stageA(1); stageA(2);   // 6 glds
    asm volatile("s_waitcnt vmcnt(4)" ::: "memory");  // g0 (+B0 partially) done
    __builtin_amdgcn_sched_barrier(0);
    __builtin_amdgcn_s_barrier();
    __builtin_amdgcn_sched_barrier(0);
    RD8(X, aBase)                      // A tile 0 (slot 0)

    // ---- main loop: bodies 0..62 (X/Y alternate), body 63 = final ----
    for (int t = 0; t < 62; t += 2) {
        GBODY(t,     X, Y, (t + 3 < NKT));
        GBODY(t + 1, Y, X, (t + 4 < NKT));
    }
    GBODY(62, X, Y, false);
    GFINAL(Y)

    // ---- epilogue: tok scales via LDS, dequant, store ----
    float* ts = (float*)(smem + NSLOT * SLOT);
    if (tid < 256) ts[tid] = tok_scale[bm * 256 + tid];
    __syncthreads();

    const int cl = l & 31;
    const int rg4 = (l >> 5) * 4;
    const int gcol0 = bn * 256 + wc * 64;
    float cs[2], bb[2];
#pragma unroll
    for (int nb = 0; nb < 2; ++nb) {
        const int col = gcol0 + nb * 32 + cl;
        cs[nb] = row_scales[col] * (1.0f / 127.0f);
        bb[nb] = bias[col];
    }
    const i32x16* accs[4][2] = {{&acc00, &acc01}, {&acc10, &acc11},
                                {&acc20, &acc21}, {&acc30, &acc31}};
#pragma unroll
    for (int mb = 0; mb < 4; ++mb) {
#pragma unroll
        for (int reg = 0; reg < 16; ++reg) {
            const int rloc = wr * 128 + mb * 32 + (reg & 3) + 8 * (reg >> 2) + rg4;
            const float tsv = ts[rloc];
            float* orow = out + (size_t)(bm * 256 + rloc) * N_OUT + gcol0 + cl;
#pragma unroll
            for (int nb = 0; nb < 2; ++nb) {
                const int a = (*accs[mb][nb])[reg];
                orow[nb * 32] = (float)a * tsv * cs[nb] + bb[nb];
            }
        }
    }
}

// ---------------- launch ----------------

extern "C" void kernel_launch(void* const* d_in, const int* in_sizes, int n_in,
                              void* d_out, int out_size, void* d_ws, size_t ws_size,
                              hipStream_t stream) {
    const float* x = (const float*)d_in[0];
    const int* wq = (const int*)d_in[1];
    const float* row_scales = (const float*)d_in[2];
    const float* bias = (const float*)d_in[3];
    float* out = (float*)d_out;

    signed char* xq8 = (signed char*)d_ws;                       // 32 MiB row-major
    signed char* xqF = xq8 + (size_t)M_TOK * K_IN;               // 32 MiB frag-tiled
    signed char* wqF = xqF + (size_t)M_TOK * K_IN;               // 16 MiB frag-tiled
    float* tok_scale = (float*)(wqF + (size_t)N_OUT * K_IN);     // 32 KiB
    (void)ws_size;

    quant_x_kernel<<<M_TOK, 256, 0, stream>>>(x, xq8, tok_scale);
    pack_w_frag_kernel<<<1024, 256, 0, stream>>>(wq, wqF);
    retile_x_kernel<<<1024, 256, 0, stream>>>(xq8, xqF);

    const int nblocks = (M_TOK / 256) * (N_OUT / 256);  // 512
    qgemm_i8b_kernel<<<nblocks, 512, 0, stream>>>(
        xqF, wqF, tok_scale, row_scales, bias, out);
}

// Round 13
// 193.476 us; speedup vs baseline: 1.0582x; 1.0582x over previous
//
#include <hip/hip_runtime.h>

#define M_TOK 8192
#define N_OUT 4096
#define K_IN  4096

#define AS1 __attribute__((address_space(1)))
#define AS3 __attribute__((address_space(3)))

typedef __attribute__((ext_vector_type(4))) int i32x4;
typedef __attribute__((ext_vector_type(16))) int i32x16;

// inline-asm ds_read_b128: invisible to compiler AA; ordering is OURS via
// counted lgkmcnt + sched_barrier(0) (rule 18).
template <int OFF>
__device__ __forceinline__ i32x4 dsri(unsigned addr) {
    i32x4 r;
    asm volatile("ds_read_b128 %0, %1 offset:%2" : "=v"(r) : "v"(addr), "n"(OFF));
    return r;
}

// ---------------- prepass 1: per-token absmax quant of x (row-major out) ----

__global__ __launch_bounds__(256) void quant_x_kernel(
    const float* __restrict__ x, signed char* __restrict__ xq,
    float* __restrict__ tok_scale)
{
    const int row = blockIdx.x;
    const float4* xr = reinterpret_cast<const float4*>(x + (size_t)row * K_IN);
    const int t = threadIdx.x;
    float4 v[4];
    float m = 0.f;
#pragma unroll
    for (int i = 0; i < 4; ++i) {
        v[i] = xr[t + 256 * i];
        m = fmaxf(m, fmaxf(fmaxf(fabsf(v[i].x), fabsf(v[i].y)),
                           fmaxf(fabsf(v[i].z), fabsf(v[i].w))));
    }
#pragma unroll
    for (int off = 32; off >= 1; off >>= 1)
        m = fmaxf(m, __shfl_xor(m, off, 64));
    __shared__ float wmax[4];
    if ((t & 63) == 0) wmax[t >> 6] = m;
    __syncthreads();
    m = fmaxf(fmaxf(wmax[0], wmax[1]), fmaxf(wmax[2], wmax[3]));
    if (t == 0) tok_scale[row] = m * (1.0f / 127.0f);
    const float inv = (m > 0.f) ? (127.0f / m) : 0.f;
    int* xqi = reinterpret_cast<int*>(xq + (size_t)row * K_IN);
#pragma unroll
    for (int i = 0; i < 4; ++i) {
        const int q0 = __float2int_rn(v[i].x * inv) & 255;
        const int q1 = __float2int_rn(v[i].y * inv) & 255;
        const int q2 = __float2int_rn(v[i].z * inv) & 255;
        const int q3 = __float2int_rn(v[i].w * inv) & 255;
        xqi[t + 256 * i] = q0 | (q1 << 8) | (q2 << 16) | (q3 << 24);
    }
}

// ---------------- prepass 1b: retile xq8 row-major -> frag-tiled -------------

__global__ __launch_bounds__(256) void retile_x_kernel(
    const signed char* __restrict__ xq8, signed char* __restrict__ xqF)
{
    __shared__ __align__(16) char lds[32768];
    const int t = threadIdx.x;
    const int rb = blockIdx.x >> 2;
    const int kc = blockIdx.x & 3;

    const size_t srcBase = (size_t)rb * 32 * K_IN + (size_t)kc * 1024;
#pragma unroll
    for (int j = 0; j < 8; ++j) {
        const int u = j * 256 + t;
        const int row = u >> 6, gc = u & 63;
        const i32x4 v = *reinterpret_cast<const i32x4*>(
            xq8 + srcBase + (size_t)row * K_IN + gc * 16);
        *reinterpret_cast<i32x4*>(
            lds + ((row * 64 + (gc ^ (row & 7))) * 16)) = v;
    }
    __syncthreads();

    const int l = t & 63;
    const int W = t >> 6;
    const int row = l & 31;
    const int hi = l >> 5;
    i32x4* dst0 = reinterpret_cast<i32x4*>(xqF) +
                  ((size_t)rb * 128 + kc * 32) * 64 + l;
#pragma unroll
    for (int i = 0; i < 8; ++i) {
        const int kfl = W * 8 + i;
        const int gc = (kfl * 2 + hi) ^ (row & 7);
        const i32x4 v = *reinterpret_cast<const i32x4*>(
            lds + ((row * 64 + gc) * 16));
        dst0[(size_t)kfl * 64] = v;
    }
}

// ---------------- prepass 2: pack Wq int32 -> int8, frag-tiled ---------------

__global__ __launch_bounds__(256) void pack_w_frag_kernel(
    const int* __restrict__ wq, signed char* __restrict__ wqF)
{
    const int t = threadIdx.x;
    const int l = t & 63;
    const int W = t >> 6;
    const int rb = blockIdx.x >> 3;
    const int pc = blockIdx.x & 7;
    const int r = rb * 32 + (l & 31);
    const int4* wr4 = reinterpret_cast<const int4*>(wq) + (size_t)r * 1024;
    i32x4* outF = reinterpret_cast<i32x4*>(wqF) + (size_t)rb * 128 * 64 + l;
#pragma unroll
    for (int q = 0; q < 4; ++q) {
        const int f = W + 4 * (pc * 4 + q);
        const int c4 = f * 8 + (l >> 5) * 4;
        i32x4 o;
#pragma unroll
        for (int j = 0; j < 4; ++j) {
            const int4 a = wr4[c4 + j];
            o[j] = (a.x & 255) | ((a.y & 255) << 8) | ((a.z & 255) << 16) | ((a.w & 255) << 24);
        }
        outF[(size_t)f * 64] = o;
    }
}

// ------- int8 GEMM R13: 256x256 tile, BK=32, ring-4, LDS = exactly 64 KiB ----
// == R12 with the prologue race FIXED: stageAB = 2 glds/tile here, so the
// prologue wait must be vmcnt(2) (leave only stage(2) in flight, confirming
// tiles 0 AND 1) -- R12's vmcnt(4) left stage(1) unconfirmed while body 0
// read tile 1 (tripwire divergence).
// Goal: 2 blocks/CU co-resident (2 x 64KB LDS <= 160KB) -> desynchronized
// barrier domains -> one block's MFMA covers the other's LDS phase.
// Per body T: entry lgkm(2) [B0,B1,A0,A1 ready] -> 4 MFMA; RD6(T+1) +
// stage(T+3); lgkm(6) [A2,A3 ready] -> 4 MFMA; boundary vmcnt(2) [confirms
// stage(T+1),(T+2); leaves stage(T+3)]; one barrier.
// Ring-4 WAR: stage(T+3) hits slot (T-1)&3; reads of tile T-1 drained by
// body T-1's lgkm(6), published by its boundary barrier.

#define NKT 128            // K tiles of 32
#define SLOTA 8192
#define SLOTB 8192

#define MFMA(a, b, c) c = __builtin_amdgcn_mfma_i32_32x32x32_i8(a, b, c, 0, 0, 0)

// 6 reads, order: B0,B1 (cluster1), A0,A1 (cluster1), A2,A3 (cluster2)
#define RD6(P, aA, bA)                          \
    P##_B0 = dsri<0>(bA);                       \
    P##_B1 = dsri<1024>(bA);                    \
    P##_A0 = dsri<0>(aA);                       \
    P##_A1 = dsri<1024>(aA);                    \
    P##_A2 = dsri<2048>(aA);                    \
    P##_A3 = dsri<3072>(aA);

#define CL4a(P)                                               \
    MFMA(P##_A0, P##_B0, acc00); MFMA(P##_A0, P##_B1, acc01); \
    MFMA(P##_A1, P##_B0, acc10); MFMA(P##_A1, P##_B1, acc11);

#define CL4b(P)                                               \
    MFMA(P##_A2, P##_B0, acc20); MFMA(P##_A2, P##_B1, acc21); \
    MFMA(P##_A3, P##_B0, acc30); MFMA(P##_A3, P##_B1, acc31);

#define GBODY(T, C, N, DO_STAGE)                                          \
    {                                                                     \
        asm volatile("s_waitcnt lgkmcnt(2)" ::: "memory");                \
        __builtin_amdgcn_sched_barrier(0);                                \
        __builtin_amdgcn_s_setprio(1);                                    \
        CL4a(C)                                                           \
        __builtin_amdgcn_s_setprio(0);                                    \
        __builtin_amdgcn_sched_barrier(0);                                \
        const unsigned aN_ = aBase + (unsigned)((((T) + 1) & 3) * SLOTA); \
        const unsigned bN_ = bBase + (unsigned)((((T) + 1) & 3) * SLOTB); \
        RD6(N, aN_, bN_)                                                  \
        if (DO_STAGE) stageAB((T) + 3);                                   \
        asm volatile("s_waitcnt lgkmcnt(6)" ::: "memory");                \
        __builtin_amdgcn_sched_barrier(0);                                \
        __builtin_amdgcn_s_setprio(1);                                    \
        CL4b(C)                                                           \
        __builtin_amdgcn_s_setprio(0);                                    \
        __builtin_amdgcn_sched_barrier(0);                                \
        if (DO_STAGE) { asm volatile("s_waitcnt vmcnt(2)" ::: "memory"); }\
        else          { asm volatile("s_waitcnt vmcnt(0)" ::: "memory"); }\
        __builtin_amdgcn_sched_barrier(0);                                \
        __builtin_amdgcn_s_barrier();                                     \
        __builtin_amdgcn_sched_barrier(0);                                \
    }

#define GFINAL(C)                                                         \
    {                                                                     \
        asm volatile("s_waitcnt lgkmcnt(2)" ::: "memory");                \
        __builtin_amdgcn_sched_barrier(0);                                \
        __builtin_amdgcn_s_setprio(1);                                    \
        CL4a(C)                                                           \
        __builtin_amdgcn_s_setprio(0);                                    \
        asm volatile("s_waitcnt lgkmcnt(0)" ::: "memory");                \
        __builtin_amdgcn_sched_barrier(0);                                \
        __builtin_amdgcn_s_setprio(1);                                    \
        CL4b(C)                                                           \
        __builtin_amdgcn_s_setprio(0);                                    \
        __builtin_amdgcn_sched_barrier(0);                                \
    }

__global__ __launch_bounds__(512, 2) void qgemm_i8c_kernel(
    const signed char* __restrict__ xqF,
    const signed char* __restrict__ wqF,
    const float* __restrict__ tok_scale,
    const float* __restrict__ row_scales,
    const float* __restrict__ bias,
    float* __restrict__ out)
{
    __shared__ __align__(16) char smem[65536];  // A [0,32K): 4 x 8KB; B [32K,64K): 4 x 8KB

    const int tid = threadIdx.x;
    const int l = tid & 63;
    const int w = tid >> 6;      // 0..7
    const int wr = w >> 2;       // 0..1
    const int wc = w & 3;        // 0..3

    // XCD-aware bijective swizzle (nwg = 512, 512 % 8 == 0)
    const int bid = blockIdx.x;
    const int swz = (bid & 7) * 64 + (bid >> 3);
    const int bm = swz >> 4;     // 0..31
    const int bn = swz & 15;     // 0..15

    // ---- staging: wave w stages A frag w and B frag w of each tile ----
    const signed char* aS = xqF + ((size_t)(bm * 8 + w) * 128) * 1024 + (size_t)l * 16;
    const signed char* bS = wqF + ((size_t)(bn * 8 + w) * 128) * 1024 + (size_t)l * 16;
    char* aDst = smem + w * 1024;
    char* bDst = smem + 32768 + w * 1024;

    auto stageAB = [&](int tt) {
        __builtin_amdgcn_global_load_lds(
            (const AS1 void*)(aS + (size_t)tt * 1024),
            (AS3 void*)(aDst + (tt & 3) * SLOTA), 16, 0, 0);
        __builtin_amdgcn_global_load_lds(
            (const AS1 void*)(bS + (size_t)tt * 1024),
            (AS3 void*)(bDst + (tt & 3) * SLOTB), 16, 0, 0);
    };

    // ---- fragment-linear ds_read bases ----
    const unsigned sbase = (unsigned)(uintptr_t)(AS3 char*)smem;
    const unsigned aBase = sbase + (unsigned)(wr * 4096 + l * 16);            // + slot + mb*1024
    const unsigned bBase = sbase + 32768u + (unsigned)(wc * 2048 + l * 16);   // + slot + nb*1024

    i32x16 acc00 = {0}, acc01 = {0}, acc10 = {0}, acc11 = {0};
    i32x16 acc20 = {0}, acc21 = {0}, acc30 = {0}, acc31 = {0};

    i32x4 X_A0, X_A1, X_A2, X_A3, X_B0, X_B1;
    i32x4 Y_A0, Y_A1, Y_A2, Y_A3, Y_B0, Y_B1;

    // ---- prologue: stage tiles 0,1,2 (6 glds); vmcnt(2) confirms tiles 0 AND 1
    //      (leaves only stage(2)'s 2 glds in flight) -- the R12 race fix.
    stageAB(0); stageAB(1); stageAB(2);
    asm volatile("s_waitcnt vmcnt(2)" ::: "memory");
    __builtin_amdgcn_sched_barrier(0);
    __builtin_amdgcn_s_barrier();
    __builtin_amdgcn_sched_barrier(0);
    RD6(X, aBase, bBase)

    // ---- main loop: bodies 0..125 (X/Y alternate); 126 no-stage; 127 final ----
    for (int t = 0; t < 126; t += 2) {
        GBODY(t,     X, Y, (t + 3 < NKT));
        GBODY(t + 1, Y, X, (t + 4 < NKT));
    }
    GBODY(126, X, Y, false);
    GFINAL(Y)

    // ---- epilogue: dequant (tok_scale via global, L2-hot), store ----
    const int cl = l & 31;
    const int rg4 = (l >> 5) * 4;
    const int gcol0 = bn * 256 + wc * 64;
    const float* tsrow = tok_scale + bm * 256 + wr * 128;
    float cs[2], bb[2];
#pragma unroll
    for (int nb = 0; nb < 2; ++nb) {
        const int col = gcol0 + nb * 32 + cl;
        cs[nb] = row_scales[col] * (1.0f / 127.0f);
        bb[nb] = bias[col];
    }
    const i32x16* accs[4][2] = {{&acc00, &acc01}, {&acc10, &acc11},
                                {&acc20, &acc21}, {&acc30, &acc31}};
#pragma unroll
    for (int mb = 0; mb < 4; ++mb) {
#pragma unroll
        for (int reg = 0; reg < 16; ++reg) {
            const int rloc = wr * 128 + mb * 32 + (reg & 3) + 8 * (reg >> 2) + rg4;
            const float tsv = tsrow[mb * 32 + (reg & 3) + 8 * (reg >> 2) + rg4];
            float* orow = out + (size_t)(bm * 256 + rloc) * N_OUT + gcol0 + cl;
#pragma unroll
            for (int nb = 0; nb < 2; ++nb) {
                const int a = (*accs[mb][nb])[reg];
                orow[nb * 32] = (float)a * tsv * cs[nb] + bb[nb];
            }
        }
    }
}

// ---------------- launch ----------------

extern "C" void kernel_launch(void* const* d_in, const int* in_sizes, int n_in,
                              void* d_out, int out_size, void* d_ws, size_t ws_size,
                              hipStream_t stream) {
    const float* x = (const float*)d_in[0];
    const int* wq = (const int*)d_in[1];
    const float* row_scales = (const float*)d_in[2];
    const float* bias = (const float*)d_in[3];
    float* out = (float*)d_out;

    signed char* xq8 = (signed char*)d_ws;                       // 32 MiB row-major
    signed char* xqF = xq8 + (size_t)M_TOK * K_IN;               // 32 MiB frag-tiled
    signed char* wqF = xqF + (size_t)M_TOK * K_IN;               // 16 MiB frag-tiled
    float* tok_scale = (float*)(wqF + (size_t)N_OUT * K_IN);     // 32 KiB
    (void)ws_size;

    quant_x_kernel<<<M_TOK, 256, 0, stream>>>(x, xq8, tok_scale);
    pack_w_frag_kernel<<<1024, 256, 0, stream>>>(wq, wqF);
    retile_x_kernel<<<1024, 256, 0, stream>>>(xq8, xqF);

    const int nblocks = (M_TOK / 256) * (N_OUT / 256);  // 512
    qgemm_i8c_kernel<<<nblocks, 512, 0, stream>>>(
        xqF, wqF, tok_scale, row_scales, bias, out);
}

// Round 14
// 192.809 us; speedup vs baseline: 1.0619x; 1.0035x over previous
//
#include <hip/hip_runtime.h>

#define M_TOK 8192
#define N_OUT 4096
#define K_IN  4096

#define AS1 __attribute__((address_space(1)))
#define AS3 __attribute__((address_space(3)))

typedef __attribute__((ext_vector_type(4))) int i32x4;
typedef __attribute__((ext_vector_type(16))) int i32x16;

// inline-asm ds_read_b128: invisible to compiler AA; ordering is OURS via
// counted lgkmcnt + sched_barrier(0) (rule 18).
template <int OFF>
__device__ __forceinline__ i32x4 dsri(unsigned addr) {
    i32x4 r;
    asm volatile("ds_read_b128 %0, %1 offset:%2" : "=v"(r) : "v"(addr), "n"(OFF));
    return r;
}

// ---------------- prepass 1: per-token absmax quant of x (row-major out) ----

__global__ __launch_bounds__(256) void quant_x_kernel(
    const float* __restrict__ x, signed char* __restrict__ xq,
    float* __restrict__ tok_scale)
{
    const int row = blockIdx.x;
    const float4* xr = reinterpret_cast<const float4*>(x + (size_t)row * K_IN);
    const int t = threadIdx.x;
    float4 v[4];
    float m = 0.f;
#pragma unroll
    for (int i = 0; i < 4; ++i) {
        v[i] = xr[t + 256 * i];
        m = fmaxf(m, fmaxf(fmaxf(fabsf(v[i].x), fabsf(v[i].y)),
                           fmaxf(fabsf(v[i].z), fabsf(v[i].w))));
    }
#pragma unroll
    for (int off = 32; off >= 1; off >>= 1)
        m = fmaxf(m, __shfl_xor(m, off, 64));
    __shared__ float wmax[4];
    if ((t & 63) == 0) wmax[t >> 6] = m;
    __syncthreads();
    m = fmaxf(fmaxf(wmax[0], wmax[1]), fmaxf(wmax[2], wmax[3]));
    if (t == 0) tok_scale[row] = m * (1.0f / 127.0f);
    const float inv = (m > 0.f) ? (127.0f / m) : 0.f;
    int* xqi = reinterpret_cast<int*>(xq + (size_t)row * K_IN);
#pragma unroll
    for (int i = 0; i < 4; ++i) {
        const int q0 = __float2int_rn(v[i].x * inv) & 255;
        const int q1 = __float2int_rn(v[i].y * inv) & 255;
        const int q2 = __float2int_rn(v[i].z * inv) & 255;
        const int q3 = __float2int_rn(v[i].w * inv) & 255;
        xqi[t + 256 * i] = q0 | (q1 << 8) | (q2 << 16) | (q3 << 24);
    }
}

// ---------------- prepass 1b: retile xq8 row-major -> frag-tiled -------------

__global__ __launch_bounds__(256) void retile_x_kernel(
    const signed char* __restrict__ xq8, signed char* __restrict__ xqF)
{
    __shared__ __align__(16) char lds[32768];
    const int t = threadIdx.x;
    const int rb = blockIdx.x >> 2;
    const int kc = blockIdx.x & 3;

    const size_t srcBase = (size_t)rb * 32 * K_IN + (size_t)kc * 1024;
#pragma unroll
    for (int j = 0; j < 8; ++j) {
        const int u = j * 256 + t;
        const int row = u >> 6, gc = u & 63;
        const i32x4 v = *reinterpret_cast<const i32x4*>(
            xq8 + srcBase + (size_t)row * K_IN + gc * 16);
        *reinterpret_cast<i32x4*>(
            lds + ((row * 64 + (gc ^ (row & 7))) * 16)) = v;
    }
    __syncthreads();

    const int l = t & 63;
    const int W = t >> 6;
    const int row = l & 31;
    const int hi = l >> 5;
    i32x4* dst0 = reinterpret_cast<i32x4*>(xqF) +
                  ((size_t)rb * 128 + kc * 32) * 64 + l;
#pragma unroll
    for (int i = 0; i < 8; ++i) {
        const int kfl = W * 8 + i;
        const int gc = (kfl * 2 + hi) ^ (row & 7);
        const i32x4 v = *reinterpret_cast<const i32x4*>(
            lds + ((row * 64 + gc) * 16));
        dst0[(size_t)kfl * 64] = v;
    }
}

// ---------------- prepass 2: pack Wq int32 -> int8, frag-tiled ---------------

__global__ __launch_bounds__(256) void pack_w_frag_kernel(
    const int* __restrict__ wq, signed char* __restrict__ wqF)
{
    const int t = threadIdx.x;
    const int l = t & 63;
    const int W = t >> 6;
    const int rb = blockIdx.x >> 3;
    const int pc = blockIdx.x & 7;
    const int r = rb * 32 + (l & 31);
    const int4* wr4 = reinterpret_cast<const int4*>(wq) + (size_t)r * 1024;
    i32x4* outF = reinterpret_cast<i32x4*>(wqF) + (size_t)rb * 128 * 64 + l;
#pragma unroll
    for (int q = 0; q < 4; ++q) {
        const int f = W + 4 * (pc * 4 + q);
        const int c4 = f * 8 + (l >> 5) * 4;
        i32x4 o;
#pragma unroll
        for (int j = 0; j < 4; ++j) {
            const int4 a = wr4[c4 + j];
            o[j] = (a.x & 255) | ((a.y & 255) << 8) | ((a.z & 255) << 16) | ((a.w & 255) << 24);
        }
        outF[(size_t)f * 64] = o;
    }
}

// ------- int8 GEMM R14: 256x256 tile, BK=32, RING-8, LDS = 128 KiB -----------
// R13 established: VGPRs (224/wave -> 256 quantum) cap us at 1 block/CU, so
// the 128KB LDS is free. R14 single change: ring 4 -> 8 slots, stage depth
// T+3 -> T+7, boundary vmcnt(2) -> vmcnt(10). stage(T+2) is now confirmed
// ~5 bodies (~6000 cyc) after issue -> queued-HBM latency fully hidden
// (theory: the ~450 cyc/body unexplained gap was the boundary vmcnt racing
// loaded-HBM latency; FETCH=147MB shows staging misses L2 often).
// Per body T: entry lgkm(2) [B0,B1,A0,A1 ready] -> 4 MFMA; RD6(T+1) +
// stage(T+7); lgkm(6) [A2,A3 ready] -> 4 MFMA; boundary vmcnt(VM); barrier.
// Tail VM: 10,10,...,10 (T<=120), then 8,6,4,2,0,0 (T=121..126).
// WAR: stage(T+7) writes slot (T-1)&7; reads of tile T-1 are lgkm-drained by
// body T-1's lgkm(6), published by its boundary barrier. Race-free.

#define NKT 128            // K tiles of 32
#define SLOTA 8192
#define SLOTB 8192

#define MFMA(a, b, c) c = __builtin_amdgcn_mfma_i32_32x32x32_i8(a, b, c, 0, 0, 0)

// 6 reads, order: B0,B1 (cluster1), A0,A1 (cluster1), A2,A3 (cluster2)
#define RD6(P, aA, bA)                          \
    P##_B0 = dsri<0>(bA);                       \
    P##_B1 = dsri<1024>(bA);                    \
    P##_A0 = dsri<0>(aA);                       \
    P##_A1 = dsri<1024>(aA);                    \
    P##_A2 = dsri<2048>(aA);                    \
    P##_A3 = dsri<3072>(aA);

#define CL4a(P)                                               \
    MFMA(P##_A0, P##_B0, acc00); MFMA(P##_A0, P##_B1, acc01); \
    MFMA(P##_A1, P##_B0, acc10); MFMA(P##_A1, P##_B1, acc11);

#define CL4b(P)                                               \
    MFMA(P##_A2, P##_B0, acc20); MFMA(P##_A2, P##_B1, acc21); \
    MFMA(P##_A3, P##_B0, acc30); MFMA(P##_A3, P##_B1, acc31);

#define GBODY(T, C, N, DO_STAGE, VM)                                      \
    {                                                                     \
        asm volatile("s_waitcnt lgkmcnt(2)" ::: "memory");                \
        __builtin_amdgcn_sched_barrier(0);                                \
        __builtin_amdgcn_s_setprio(1);                                    \
        CL4a(C)                                                           \
        __builtin_amdgcn_s_setprio(0);                                    \
        __builtin_amdgcn_sched_barrier(0);                                \
        const unsigned aN_ = aBase + (unsigned)((((T) + 1) & 7) * SLOTA); \
        const unsigned bN_ = bBase + (unsigned)((((T) + 1) & 7) * SLOTB); \
        RD6(N, aN_, bN_)                                                  \
        if (DO_STAGE) stageAB((T) + 7);                                   \
        asm volatile("s_waitcnt lgkmcnt(6)" ::: "memory");                \
        __builtin_amdgcn_sched_barrier(0);                                \
        __builtin_amdgcn_s_setprio(1);                                    \
        CL4b(C)                                                           \
        __builtin_amdgcn_s_setprio(0);                                    \
        __builtin_amdgcn_sched_barrier(0);                                \
        asm volatile("s_waitcnt vmcnt(" #VM ")" ::: "memory");            \
        __builtin_amdgcn_sched_barrier(0);                                \
        __builtin_amdgcn_s_barrier();                                     \
        __builtin_amdgcn_sched_barrier(0);                                \
    }

#define GFINAL(C)                                                         \
    {                                                                     \
        asm volatile("s_waitcnt lgkmcnt(2)" ::: "memory");                \
        __builtin_amdgcn_sched_barrier(0);                                \
        __builtin_amdgcn_s_setprio(1);                                    \
        CL4a(C)                                                           \
        __builtin_amdgcn_s_setprio(0);                                    \
        asm volatile("s_waitcnt lgkmcnt(0)" ::: "memory");                \
        __builtin_amdgcn_sched_barrier(0);                                \
        __builtin_amdgcn_s_setprio(1);                                    \
        CL4b(C)                                                           \
        __builtin_amdgcn_s_setprio(0);                                    \
        __builtin_amdgcn_sched_barrier(0);                                \
    }

__global__ __launch_bounds__(512, 2) void qgemm_i8r8_kernel(
    const signed char* __restrict__ xqF,
    const signed char* __restrict__ wqF,
    const float* __restrict__ tok_scale,
    const float* __restrict__ row_scales,
    const float* __restrict__ bias,
    float* __restrict__ out)
{
    __shared__ __align__(16) char smem[131072];  // A [0,64K): 8 x 8KB; B [64K,128K): 8 x 8KB

    const int tid = threadIdx.x;
    const int l = tid & 63;
    const int w = tid >> 6;      // 0..7
    const int wr = w >> 2;       // 0..1
    const int wc = w & 3;        // 0..3

    // XCD-aware bijective swizzle (nwg = 512, 512 % 8 == 0)
    const int bid = blockIdx.x;
    const int swz = (bid & 7) * 64 + (bid >> 3);
    const int bm = swz >> 4;     // 0..31
    const int bn = swz & 15;     // 0..15

    // ---- staging: wave w stages A frag w and B frag w of each tile ----
    const signed char* aS = xqF + ((size_t)(bm * 8 + w) * 128) * 1024 + (size_t)l * 16;
    const signed char* bS = wqF + ((size_t)(bn * 8 + w) * 128) * 1024 + (size_t)l * 16;
    char* aDst = smem + w * 1024;
    char* bDst = smem + 65536 + w * 1024;

    auto stageAB = [&](int tt) {
        __builtin_amdgcn_global_load_lds(
            (const AS1 void*)(aS + (size_t)tt * 1024),
            (AS3 void*)(aDst + (tt & 7) * SLOTA), 16, 0, 0);
        __builtin_amdgcn_global_load_lds(
            (const AS1 void*)(bS + (size_t)tt * 1024),
            (AS3 void*)(bDst + (tt & 7) * SLOTB), 16, 0, 0);
    };

    // ---- fragment-linear ds_read bases ----
    const unsigned sbase = (unsigned)(uintptr_t)(AS3 char*)smem;
    const unsigned aBase = sbase + (unsigned)(wr * 4096 + l * 16);            // + slot + mb*1024
    const unsigned bBase = sbase + 65536u + (unsigned)(wc * 2048 + l * 16);   // + slot + nb*1024

    i32x16 acc00 = {0}, acc01 = {0}, acc10 = {0}, acc11 = {0};
    i32x16 acc20 = {0}, acc21 = {0}, acc30 = {0}, acc31 = {0};

    i32x4 X_A0, X_A1, X_A2, X_A3, X_B0, X_B1;
    i32x4 Y_A0, Y_A1, Y_A2, Y_A3, Y_B0, Y_B1;

    // ---- prologue: stage tiles 0..6 (14 glds); vmcnt(10) confirms tiles 0,1 ----
    stageAB(0); stageAB(1); stageAB(2); stageAB(3);
    stageAB(4); stageAB(5); stageAB(6);
    asm volatile("s_waitcnt vmcnt(10)" ::: "memory");
    __builtin_amdgcn_sched_barrier(0);
    __builtin_amdgcn_s_barrier();
    __builtin_amdgcn_sched_barrier(0);
    RD6(X, aBase, bBase)

    // ---- main loop: bodies 0..119 (VM=10), tail 120..126, body 127 = final ----
    for (int t = 0; t < 120; t += 2) {
        GBODY(t,     X, Y, true, 10);
        GBODY(t + 1, Y, X, true, 10);
    }
    GBODY(120, X, Y, true, 10);   // stages tile 127 (the last)
    GBODY(121, Y, X, false, 8);
    GBODY(122, X, Y, false, 6);
    GBODY(123, Y, X, false, 4);
    GBODY(124, X, Y, false, 2);
    GBODY(125, Y, X, false, 0);
    GBODY(126, X, Y, false, 0);
    GFINAL(Y)

    // ---- epilogue: dequant (tok_scale via global, L2-hot), store ----
    const int cl = l & 31;
    const int rg4 = (l >> 5) * 4;
    const int gcol0 = bn * 256 + wc * 64;
    const float* tsrow = tok_scale + bm * 256 + wr * 128;
    float cs[2], bb[2];
#pragma unroll
    for (int nb = 0; nb < 2; ++nb) {
        const int col = gcol0 + nb * 32 + cl;
        cs[nb] = row_scales[col] * (1.0f / 127.0f);
        bb[nb] = bias[col];
    }
    const i32x16* accs[4][2] = {{&acc00, &acc01}, {&acc10, &acc11},
                                {&acc20, &acc21}, {&acc30, &acc31}};
#pragma unroll
    for (int mb = 0; mb < 4; ++mb) {
#pragma unroll
        for (int reg = 0; reg < 16; ++reg) {
            const int rloc = wr * 128 + mb * 32 + (reg & 3) + 8 * (reg >> 2) + rg4;
            const float tsv = tsrow[mb * 32 + (reg & 3) + 8 * (reg >> 2) + rg4];
            float* orow = out + (size_t)(bm * 256 + rloc) * N_OUT + gcol0 + cl;
#pragma unroll
            for (int nb = 0; nb < 2; ++nb) {
                const int a = (*accs[mb][nb])[reg];
                orow[nb * 32] = (float)a * tsv * cs[nb] + bb[nb];
            }
        }
    }
}

// ---------------- launch ----------------

extern "C" void kernel_launch(void* const* d_in, const int* in_sizes, int n_in,
                              void* d_out, int out_size, void* d_ws, size_t ws_size,
                              hipStream_t stream) {
    const float* x = (const float*)d_in[0];
    const int* wq = (const int*)d_in[1];
    const float* row_scales = (const float*)d_in[2];
    const float* bias = (const float*)d_in[3];
    float* out = (float*)d_out;

    signed char* xq8 = (signed char*)d_ws;                       // 32 MiB row-major
    signed char* xqF = xq8 + (size_t)M_TOK * K_IN;               // 32 MiB frag-tiled
    signed char* wqF = xqF + (size_t)M_TOK * K_IN;               // 16 MiB frag-tiled
    float* tok_scale = (float*)(wqF + (size_t)N_OUT * K_IN);     // 32 KiB
    (void)ws_size;

    quant_x_kernel<<<M_TOK, 256, 0, stream>>>(x, xq8, tok_scale);
    pack_w_frag_kernel<<<1024, 256, 0, stream>>>(wq, wqF);
    retile_x_kernel<<<1024, 256, 0, stream>>>(xq8, xqF);

    const int nblocks = (M_TOK / 256) * (N_OUT / 256);  // 512
    qgemm_i8r8_kernel<<<nblocks, 512, 0, stream>>>(
        xqF, wqF, tok_scale, row_scales, bias, out);
}